// Round 6
// baseline (342.699 us; speedup 1.0000x reference)
//
#include <hip/hip_runtime.h>
#include <hip/hip_bf16.h>

// Problem constants
#define NB 64   // batch N
#define CC 64   // in channels C
#define TT 256  // time T
#define VV 25   // vertices V (= U)
#define HH 8    // heads H
#define OO 64   // out channels O
#define TV (TT*VV)   // 6400
#define UV (VV*VV)   // 625

// ---------------------------------------------------------------------------
// Kernel P: transpose Wv -> WvT[c][o]  (contiguous per-c rows -> wave-uniform
// scalar loads in k_vproj's inner loop). grid = 16 blocks.
// ---------------------------------------------------------------------------
__global__ __launch_bounds__(256) void k_prep(const float* __restrict__ Wv,
                                              float* __restrict__ WvT) {
    int i = blockIdx.x * 256 + threadIdx.x;   // 0..4095
    int o = i >> 6, c = i & 63;
    WvT[c * OO + o] = Wv[o * CC + c];
}

// ---------------------------------------------------------------------------
// Kernel V: v-projection. vv[n,o,t,v] = sum_c Wv[o,c]*x[n,c,t,v] + bv[o]
// grid = N*25 = 1600 blocks, 256 threads; thread = one tv position, all 64 o
// in 16 float4 accumulators.
// Round-5 pathology: compiler fissioned the o-loop and re-read x ~16x
// (VGPR=40, 88us, VALUBusy 27%). Fix: asm-barrier each loaded x value —
// volatile asm cannot be duplicated, so fission/remat of the x loads is
// structurally impossible; accumulators must stay live (fits 128-VGPR budget
// from __launch_bounds__(256,4)).
// ---------------------------------------------------------------------------
__global__ __launch_bounds__(256, 4) void k_vproj(const float* __restrict__ x,
                                                  const float* __restrict__ WvT,
                                                  const float* __restrict__ bv,
                                                  float* __restrict__ vv) {
    int blk = blockIdx.x;
    int n = blk / 25, ch = blk % 25;
    int tv = ch * 256 + threadIdx.x;

    const float*  xs = x + (size_t)n * CC * TV + tv;
    const float4* W4 = (const float4*)WvT;      // [c][o/4], 16B-aligned
    const float4* b4 = (const float4*)bv;

    float4 a[OO / 4];                            // 64 accs, static indices only
#pragma unroll
    for (int j = 0; j < OO / 4; ++j) a[j] = b4[j];

#pragma unroll 1
    for (int c = 0; c < CC; c += 4) {            // 16 iterations, body pinned
        float x0 = xs[(size_t)(c + 0) * TV];     // 4 coalesced loads in flight
        float x1 = xs[(size_t)(c + 1) * TV];
        float x2 = xs[(size_t)(c + 2) * TV];
        float x3 = xs[(size_t)(c + 3) * TV];
        // Opaque barrier: pins x0-3 as single-def VGPR values; the compiler
        // can neither re-load nor rematerialize them per o-group.
        asm volatile("" : "+v"(x0), "+v"(x1), "+v"(x2), "+v"(x3));
#pragma unroll
        for (int j = 0; j < OO / 4; ++j) {       // uniform -> s_load weights
            float4 w0 = W4[(c + 0) * (OO / 4) + j];
            float4 w1 = W4[(c + 1) * (OO / 4) + j];
            float4 w2 = W4[(c + 2) * (OO / 4) + j];
            float4 w3 = W4[(c + 3) * (OO / 4) + j];
            a[j].x += w0.x * x0; a[j].y += w0.y * x0; a[j].z += w0.z * x0; a[j].w += w0.w * x0;
            a[j].x += w1.x * x1; a[j].y += w1.y * x1; a[j].z += w1.z * x1; a[j].w += w1.w * x1;
            a[j].x += w2.x * x2; a[j].y += w2.y * x2; a[j].z += w2.z * x2; a[j].w += w2.w * x2;
            a[j].x += w3.x * x3; a[j].y += w3.y * x3; a[j].z += w3.z * x3; a[j].w += w3.w * x3;
        }
    }

    float* dst = vv + (size_t)n * OO * TV + tv;
#pragma unroll
    for (int j = 0; j < OO / 4; ++j) {           // coalesced per-o-plane stores
        dst[(size_t)(4 * j + 0) * TV] = a[j].x;
        dst[(size_t)(4 * j + 1) * TV] = a[j].y;
        dst[(size_t)(4 * j + 2) * TV] = a[j].z;
        dst[(size_t)(4 * j + 3) * TV] = a[j].w;
    }
}

// ---------------------------------------------------------------------------
// Kernel M: x temporal mean. Runs AFTER k_vproj so x is L3-resident.
// grid = N*C = 4096 blocks. Stage the 25.6 KB row coalesced into LDS,
// column-reduce (stride-25 odd -> conflict-light). Tiny register footprint.
// ---------------------------------------------------------------------------
__global__ __launch_bounds__(256) void k_mean(const float* __restrict__ x,
                                              float* __restrict__ xmean) {
    int nc  = blockIdx.x;
    int tid = threadIdx.x;
    __shared__ float tile[TV];                 // 25.6 KB
    __shared__ float part[8 * VV];

    const float4* g4 = (const float4*)(x + (size_t)nc * TV);
    float4*       t4 = (float4*)tile;
    for (int i = tid; i < TV / 4; i += 256) t4[i] = g4[i];   // coalesced
    __syncthreads();

    if (tid < 8 * VV) {                        // 200 active: g=0..7, v=0..24
        int g = tid / VV, v = tid % VV;
        float s = 0.0f;
#pragma unroll
        for (int j = 0; j < 32; ++j) s += tile[(g * 32 + j) * VV + v];
        part[g * VV + v] = s;
    }
    __syncthreads();

    if (tid < VV) {
        float s = 0.0f;
#pragma unroll
        for (int g = 0; g < 8; ++g) s += part[g * VV + tid];
        xmean[(size_t)nc * VV + tid] = s * (1.0f / TT);
    }
}

// ---------------------------------------------------------------------------
// Kernel B: masked[n,o,u,v] =
//     alpha*(sum_h Wr[o,h]*tanh(q[n,h,u]-k[n,h,v]) + br[o]) + A[u,v]
// grid = N blocks. ~4 us.
// ---------------------------------------------------------------------------
__global__ __launch_bounds__(256) void k_masked(
        const float* __restrict__ xmean, const float* __restrict__ A,
        const float* __restrict__ alpha_p,
        const float* __restrict__ Wq, const float* __restrict__ bq,
        const float* __restrict__ Wk, const float* __restrict__ bk,
        const float* __restrict__ Wr, const float* __restrict__ br,
        float* __restrict__ masked) {
    int n = blockIdx.x, tid = threadIdx.x;
    __shared__ float xm[CC * VV];
    __shared__ float qs[HH * VV];
    __shared__ float ks[HH * VV];
    __shared__ float attn[HH * UV];

    for (int i = tid; i < CC * VV; i += 256)
        xm[i] = xmean[(size_t)n * CC * VV + i];
    __syncthreads();

    for (int i = tid; i < 2 * HH * VV; i += 256) {   // 400 q/k outputs
        int isK = i >= HH * VV;
        int hv = isK ? i - HH * VV : i;
        int h = hv / VV, v = hv % VV;
        const float* W = isK ? Wk : Wq;
        float s = isK ? bk[h] : bq[h];
        for (int c = 0; c < CC; ++c) s += xm[c * VV + v] * W[h * CC + c];
        if (isK) ks[hv] = s; else qs[hv] = s;
    }
    __syncthreads();

    for (int i = tid; i < HH * UV; i += 256) {       // 5000 tanh
        int h = i / UV, uv = i % UV, u = uv / VV, v = uv % VV;
        attn[i] = tanhf(qs[h * VV + u] - ks[h * VV + v]);
    }
    __syncthreads();

    float alpha = alpha_p[0];
    for (int i = tid; i < OO * UV; i += 256) {       // 40000 masked outputs
        int o = i / UV, uv = i % UV;
        float r = br[o];
#pragma unroll
        for (int h = 0; h < HH; ++h) r += Wr[o * HH + h] * attn[h * UV + uv];
        masked[(size_t)n * OO * UV + i] = alpha * r + A[uv];
    }
}

// ---------------------------------------------------------------------------
// Kernel C: aggregation, in-place on d_out.
// out[n,o,t,u] = sum_v masked[n,o,u,v] * vv[n,o,t,v]
// grid = N*O blocks, 256 threads (thread = t).
// Round-4/5 pathology: ~200us — per-thread 25-float arrays likely scratch'd.
// Fix: NO per-thread arrays. u chunked 5x5 -> only 5 named accumulators;
// separate in/out LDS buffers (51.2 KB -> 3 blocks/CU, 12 waves, fine);
// masked row block-uniform -> SGPR operands. ~20 VGPR total.
// ---------------------------------------------------------------------------
__global__ __launch_bounds__(256, 8) void k_aggr(float* __restrict__ io,
                                                 const float* __restrict__ masked) {
    int no = blockIdx.x;                  // n*64 + o
    int t  = threadIdx.x;
    __shared__ float bin [TV];            // 25.6 KB
    __shared__ float bout[TV];            // 25.6 KB
    float4* b4 = (float4*)bin;
    float4* o4 = (float4*)bout;
    float4* g4 = (float4*)(io + (size_t)no * TV);

    for (int i = t; i < TV / 4; i += 256) b4[i] = g4[i];   // coalesced in
    __syncthreads();

    const float* m = masked + (size_t)no * UV;   // block-uniform -> SGPR
    const float* xr = bin + t * VV;              // this thread's v-row

#pragma unroll 1
    for (int uc = 0; uc < VV; uc += 5) {         // 5 chunks of 5 u
        float a0 = 0.f, a1 = 0.f, a2 = 0.f, a3 = 0.f, a4 = 0.f;
#pragma unroll
        for (int v = 0; v < VV; ++v) {
            float xv = xr[v];                    // ds_read_b32
            a0 += m[(uc + 0) * VV + v] * xv;     // SGPR * VGPR fmacs
            a1 += m[(uc + 1) * VV + v] * xv;
            a2 += m[(uc + 2) * VV + v] * xv;
            a3 += m[(uc + 3) * VV + v] * xv;
            a4 += m[(uc + 4) * VV + v] * xv;
        }
        bout[t * VV + uc + 0] = a0;
        bout[t * VV + uc + 1] = a1;
        bout[t * VV + uc + 2] = a2;
        bout[t * VV + uc + 3] = a3;
        bout[t * VV + uc + 4] = a4;
    }
    __syncthreads();

    for (int i = t; i < TV / 4; i += 256) g4[i] = o4[i];   // coalesced out
}

// ---------------------------------------------------------------------------
extern "C" void kernel_launch(void* const* d_in, const int* in_sizes, int n_in,
                              void* d_out, int out_size, void* d_ws, size_t ws_size,
                              hipStream_t stream) {
    const float* x     = (const float*)d_in[0];
    const float* A     = (const float*)d_in[1];
    const float* alpha = (const float*)d_in[2];
    const float* Wq    = (const float*)d_in[3];
    const float* bq    = (const float*)d_in[4];
    const float* Wk    = (const float*)d_in[5];
    const float* bk    = (const float*)d_in[6];
    const float* Wv    = (const float*)d_in[7];
    const float* bv    = (const float*)d_in[8];
    const float* Wr    = (const float*)d_in[9];
    const float* br    = (const float*)d_in[10];
    float* out = (float*)d_out;

    // ws layout: masked 2,560,000 fl | xmean 102,400 fl | WvT 4,096 fl (~10.7 MB)
    float* ws     = (float*)d_ws;
    float* masked = ws;
    float* xmean  = ws + (size_t)NB * OO * UV;
    float* WvT    = xmean + (size_t)NB * CC * VV;

    k_prep  <<<(CC * OO) / 256, 256, 0, stream>>>(Wv, WvT);
    k_vproj <<<NB * 25, 256, 0, stream>>>(x, WvT, bv, out);
    k_mean  <<<NB * CC, 256, 0, stream>>>(x, xmean);   // x L3-resident now
    k_masked<<<NB, 256, 0, stream>>>(xmean, A, alpha, Wq, bq, Wk, bk, Wr, br, masked);
    k_aggr  <<<NB * OO, 256, 0, stream>>>(out, masked);
}

// Round 9
// 338.787 us; speedup vs baseline: 1.0115x; 1.0115x over previous
//
#include <hip/hip_runtime.h>
#include <hip/hip_bf16.h>

// Problem constants
#define NB 64   // batch N
#define CC 64   // in channels C
#define TT 256  // time T
#define VV 25   // vertices V (= U)
#define HH 8    // heads H
#define OO 64   // out channels O
#define TV (TT*VV)   // 6400
#define UV (VV*VV)   // 625

// ---------------------------------------------------------------------------
// Kernel P: transpose Wv -> WvT[c][o]. grid = 16 blocks.
// ---------------------------------------------------------------------------
__global__ __launch_bounds__(256) void k_prep(const float* __restrict__ Wv,
                                              float* __restrict__ WvT) {
    int i = blockIdx.x * 256 + threadIdx.x;   // 0..4095
    int o = i >> 6, c = i & 63;
    WvT[c * OO + o] = Wv[o * CC + c];
}

// ---------------------------------------------------------------------------
// Kernel V: v-projection. vv[n,o,t,v] = sum_c Wv[o,c]*x[n,c,t,v] + bv[o]
// PATHOLOGY-PROOF STRUCTURE (rounds 5/6: compiler refused >40 VGPR, via
// fission/x-re-read then via scratch'd acc array):
//   block = 128 tv positions x 2 o-halves (256 threads).
//   Each thread: 32 o-channels in EIGHT NAMED float4 accs (~50-65 VGPR
//   total) -> fits even an 8-waves/EU 64-VGPR budget, so the allocator has
//   NO occupancy reason to restructure, and no array exists to scratch.
//   oh = readfirstlane(tid>>7): provably wave-uniform -> weights/bias remain
//   s_load. Waves 2-3 re-load the same x as waves 0-1 -> L1 hits (HBM
//   traffic unchanged). asm barrier pins x values against remat.
// grid = N*50 = 3200 blocks.
// ---------------------------------------------------------------------------
__global__ __launch_bounds__(256, 4) void k_vproj(const float* __restrict__ x,
                                                  const float* __restrict__ WvT,
                                                  const float* __restrict__ bv,
                                                  float* __restrict__ vv) {
    int blk = blockIdx.x;
    int n  = blk / 50, ch = blk % 50;         // ch = 128-wide tv chunk
    int tid = threadIdx.x;
    int tvi = tid & 127;                      // tv within chunk (divergent)
    int oh  = __builtin_amdgcn_readfirstlane(tid >> 7);  // o-half, SGPR
    int tv  = ch * 128 + tvi;

    const float*  xs = x + (size_t)n * CC * TV + tv;
    const float4* W4 = (const float4*)WvT;    // [c][16 float4]
    const float4* b4 = (const float4*)bv;
    int ob = oh * 8;                          // float4 base of this o-half

    float4 a0 = b4[ob + 0], a1 = b4[ob + 1], a2 = b4[ob + 2], a3 = b4[ob + 3];
    float4 a4 = b4[ob + 4], a5 = b4[ob + 5], a6 = b4[ob + 6], a7 = b4[ob + 7];

#pragma unroll 1
    for (int c = 0; c < CC; c += 4) {         // 16 iterations, body pinned
        float x0 = xs[(size_t)(c + 0) * TV];  // 4 coalesced loads in flight
        float x1 = xs[(size_t)(c + 1) * TV];
        float x2 = xs[(size_t)(c + 2) * TV];
        float x3 = xs[(size_t)(c + 3) * TV];
        asm volatile("" : "+v"(x0), "+v"(x1), "+v"(x2), "+v"(x3));
        const float4* Wc = W4 + (size_t)c * (OO / 4) + ob;   // SGPR base
#define VP_STEP(AJ, J)                                                       \
        do {                                                                 \
            float4 w0 = Wc[J];                    /* s_load_dwordx4 */       \
            float4 w1 = Wc[(OO / 4) + (J)];                                  \
            float4 w2 = Wc[2 * (OO / 4) + (J)];                              \
            float4 w3 = Wc[3 * (OO / 4) + (J)];                              \
            AJ.x += w0.x * x0; AJ.y += w0.y * x0; AJ.z += w0.z * x0; AJ.w += w0.w * x0; \
            AJ.x += w1.x * x1; AJ.y += w1.y * x1; AJ.z += w1.z * x1; AJ.w += w1.w * x1; \
            AJ.x += w2.x * x2; AJ.y += w2.y * x2; AJ.z += w2.z * x2; AJ.w += w2.w * x2; \
            AJ.x += w3.x * x3; AJ.y += w3.y * x3; AJ.z += w3.z * x3; AJ.w += w3.w * x3; \
        } while (0)
        VP_STEP(a0, 0); VP_STEP(a1, 1); VP_STEP(a2, 2); VP_STEP(a3, 3);
        VP_STEP(a4, 4); VP_STEP(a5, 5); VP_STEP(a6, 6); VP_STEP(a7, 7);
#undef VP_STEP
    }

    // o-plane = oh*32 + 4*J + k ; oh*32*TV folds into the SGPR base.
    float* dst = vv + (size_t)n * OO * TV + (size_t)oh * 32 * TV + tv;
#define VP_ST(AJ, J)                                                         \
    dst[(size_t)(4 * (J) + 0) * TV] = AJ.x;                                  \
    dst[(size_t)(4 * (J) + 1) * TV] = AJ.y;                                  \
    dst[(size_t)(4 * (J) + 2) * TV] = AJ.z;                                  \
    dst[(size_t)(4 * (J) + 3) * TV] = AJ.w;
    VP_ST(a0, 0) VP_ST(a1, 1) VP_ST(a2, 2) VP_ST(a3, 3)
    VP_ST(a4, 4) VP_ST(a5, 5) VP_ST(a6, 6) VP_ST(a7, 7)
#undef VP_ST
}

// ---------------------------------------------------------------------------
// Kernel M: x temporal mean. grid = N*C = 4096 blocks. Stage the 25.6 KB row
// coalesced into LDS, column-reduce (stride-25 odd -> conflict-light).
// ---------------------------------------------------------------------------
__global__ __launch_bounds__(256) void k_mean(const float* __restrict__ x,
                                              float* __restrict__ xmean) {
    int nc  = blockIdx.x;
    int tid = threadIdx.x;
    __shared__ float tile[TV];                 // 25.6 KB
    __shared__ float part[8 * VV];

    const float4* g4 = (const float4*)(x + (size_t)nc * TV);
    float4*       t4 = (float4*)tile;
    for (int i = tid; i < TV / 4; i += 256) t4[i] = g4[i];   // coalesced
    __syncthreads();

    if (tid < 8 * VV) {                        // 200 active: g=0..7, v=0..24
        int g = tid / VV, v = tid % VV;
        float s = 0.0f;
#pragma unroll
        for (int j = 0; j < 32; ++j) s += tile[(g * 32 + j) * VV + v];
        part[g * VV + v] = s;
    }
    __syncthreads();

    if (tid < VV) {
        float s = 0.0f;
#pragma unroll
        for (int g = 0; g < 8; ++g) s += part[g * VV + tid];
        xmean[(size_t)nc * VV + tid] = s * (1.0f / TT);
    }
}

// ---------------------------------------------------------------------------
// Kernel B: masked[n,o,u,v] =
//     alpha*(sum_h Wr[o,h]*tanh(q[n,h,u]-k[n,h,v]) + br[o]) + A[u,v]
// grid = N blocks. ~4 us.
// ---------------------------------------------------------------------------
__global__ __launch_bounds__(256) void k_masked(
        const float* __restrict__ xmean, const float* __restrict__ A,
        const float* __restrict__ alpha_p,
        const float* __restrict__ Wq, const float* __restrict__ bq,
        const float* __restrict__ Wk, const float* __restrict__ bk,
        const float* __restrict__ Wr, const float* __restrict__ br,
        float* __restrict__ masked) {
    int n = blockIdx.x, tid = threadIdx.x;
    __shared__ float xm[CC * VV];
    __shared__ float qs[HH * VV];
    __shared__ float ks[HH * VV];
    __shared__ float attn[HH * UV];

    for (int i = tid; i < CC * VV; i += 256)
        xm[i] = xmean[(size_t)n * CC * VV + i];
    __syncthreads();

    for (int i = tid; i < 2 * HH * VV; i += 256) {   // 400 q/k outputs
        int isK = i >= HH * VV;
        int hv = isK ? i - HH * VV : i;
        int h = hv / VV, v = hv % VV;
        const float* W = isK ? Wk : Wq;
        float s = isK ? bk[h] : bq[h];
        for (int c = 0; c < CC; ++c) s += xm[c * VV + v] * W[h * CC + c];
        if (isK) ks[hv] = s; else qs[hv] = s;
    }
    __syncthreads();

    for (int i = tid; i < HH * UV; i += 256) {       // 5000 tanh
        int h = i / UV, uv = i % UV, u = uv / VV, v = uv % VV;
        attn[i] = tanhf(qs[h * VV + u] - ks[h * VV + v]);
    }
    __syncthreads();

    float alpha = alpha_p[0];
    for (int i = tid; i < OO * UV; i += 256) {       // 40000 masked outputs
        int o = i / UV, uv = i % UV;
        float r = br[o];
#pragma unroll
        for (int h = 0; h < HH; ++h) r += Wr[o * HH + h] * attn[h * UV + uv];
        masked[(size_t)n * OO * UV + i] = alpha * r + A[uv];
    }
}

// ---------------------------------------------------------------------------
// Kernel C: aggregation, in-place on d_out.
// out[n,o,t,u] = sum_v masked[n,o,u,v] * vv[n,o,t,v]
// grid = N*O blocks, 256 threads (thread = t). No per-thread arrays (5 named
// accs per u-chunk); separate in/out LDS buffers; masked row block-uniform
// -> SGPR operands.
// ---------------------------------------------------------------------------
__global__ __launch_bounds__(256, 8) void k_aggr(float* __restrict__ io,
                                                 const float* __restrict__ masked) {
    int no = blockIdx.x;                  // n*64 + o
    int t  = threadIdx.x;
    __shared__ float bin [TV];            // 25.6 KB
    __shared__ float bout[TV];            // 25.6 KB
    float4* b4 = (float4*)bin;
    float4* o4 = (float4*)bout;
    float4* g4 = (float4*)(io + (size_t)no * TV);

    for (int i = t; i < TV / 4; i += 256) b4[i] = g4[i];   // coalesced in
    __syncthreads();

    const float* m = masked + (size_t)no * UV;   // block-uniform -> SGPR
    const float* xr = bin + t * VV;              // this thread's v-row

#pragma unroll 1
    for (int uc = 0; uc < VV; uc += 5) {         // 5 chunks of 5 u
        float a0 = 0.f, a1 = 0.f, a2 = 0.f, a3 = 0.f, a4 = 0.f;
#pragma unroll
        for (int v = 0; v < VV; ++v) {
            float xv = xr[v];                    // ds_read_b32
            a0 += m[(uc + 0) * VV + v] * xv;     // SGPR * VGPR fmacs
            a1 += m[(uc + 1) * VV + v] * xv;
            a2 += m[(uc + 2) * VV + v] * xv;
            a3 += m[(uc + 3) * VV + v] * xv;
            a4 += m[(uc + 4) * VV + v] * xv;
        }
        bout[t * VV + uc + 0] = a0;
        bout[t * VV + uc + 1] = a1;
        bout[t * VV + uc + 2] = a2;
        bout[t * VV + uc + 3] = a3;
        bout[t * VV + uc + 4] = a4;
    }
    __syncthreads();

    for (int i = t; i < TV / 4; i += 256) g4[i] = o4[i];   // coalesced out
}

// ---------------------------------------------------------------------------
extern "C" void kernel_launch(void* const* d_in, const int* in_sizes, int n_in,
                              void* d_out, int out_size, void* d_ws, size_t ws_size,
                              hipStream_t stream) {
    const float* x     = (const float*)d_in[0];
    const float* A     = (const float*)d_in[1];
    const float* alpha = (const float*)d_in[2];
    const float* Wq    = (const float*)d_in[3];
    const float* bq    = (const float*)d_in[4];
    const float* Wk    = (const float*)d_in[5];
    const float* bk    = (const float*)d_in[6];
    const float* Wv    = (const float*)d_in[7];
    const float* bv    = (const float*)d_in[8];
    const float* Wr    = (const float*)d_in[9];
    const float* br    = (const float*)d_in[10];
    float* out = (float*)d_out;

    // ws layout: masked 2,560,000 fl | xmean 102,400 fl | WvT 4,096 fl (~10.7 MB)
    float* ws     = (float*)d_ws;
    float* masked = ws;
    float* xmean  = ws + (size_t)NB * OO * UV;
    float* WvT    = xmean + (size_t)NB * CC * VV;

    k_prep  <<<(CC * OO) / 256, 256, 0, stream>>>(Wv, WvT);
    k_vproj <<<NB * 50, 256, 0, stream>>>(x, WvT, bv, out);
    k_mean  <<<NB * CC, 256, 0, stream>>>(x, xmean);
    k_masked<<<NB, 256, 0, stream>>>(xmean, A, alpha, Wq, bq, Wk, bk, Wr, br, masked);
    k_aggr  <<<NB * OO, 256, 0, stream>>>(out, masked);
}